// Round 1
// 170.020 us; speedup vs baseline: 1.0564x; 1.0564x over previous
//
#include <hip/hip_runtime.h>
#include <hip/hip_fp16.h>
#include <math.h>

#define DFEAT 128
#define CAP 64
typedef unsigned long long u64;
typedef unsigned int u32;
typedef unsigned short u16;
#define ENDK 0xFFFFFFFFFFFFFFFFULL

// K1, split by block range. Bin blocks FIRST so the latency-bound atomic phase
// fills the CUs immediately and the BW-bound ELU phase overlaps behind it.
//  - blocks [0, binBlocks): linked-list binning, 4 strided edges per thread
//      (4 atomicExch in flight per lane -> 4x memory-level parallelism)
//  - blocks [binBlocks, ..): emb2[i] = fp16( 2 * elu(x[i] * w[i % D]) )
__global__ void fused_bin_elu_kernel(const float* __restrict__ x,
                                     const float* __restrict__ w,
                                     __half* __restrict__ emb2, int total4,
                                     const int* __restrict__ src,
                                     const int* __restrict__ dst, int E,
                                     u64* __restrict__ head,
                                     u64* __restrict__ nxt,
                                     int binBlocks) {
    if ((int)blockIdx.x < binBlocks) {
        int base = blockIdx.x * 1024 + threadIdx.x;   // 4 edges, stride 256
        int e0 = base, e1 = base + 256, e2 = base + 512, e3 = base + 768;
        bool a0 = e0 < E, a1 = e1 < E, a2 = e2 < E, a3 = e3 < E;
        int s0 = 0, s1 = 0, s2 = 0, s3 = 0, d0 = 0, d1 = 0, d2 = 0, d3 = 0;
        if (a0) { s0 = src[e0]; d0 = dst[e0]; }
        if (a1) { s1 = src[e1]; d1 = dst[e1]; }
        if (a2) { s2 = src[e2]; d2 = dst[e2]; }
        if (a3) { s3 = src[e3]; d3 = dst[e3]; }
        u64 o0 = 0, o1 = 0, o2 = 0, o3 = 0;
        if (a0) o0 = atomicExch(&head[d0], ((u64)(u32)s0 << 32) | (u32)e0);
        if (a1) o1 = atomicExch(&head[d1], ((u64)(u32)s1 << 32) | (u32)e1);
        if (a2) o2 = atomicExch(&head[d2], ((u64)(u32)s2 << 32) | (u32)e2);
        if (a3) o3 = atomicExch(&head[d3], ((u64)(u32)s3 << 32) | (u32)e3);
        if (a0) nxt[e0] = o0;
        if (a1) nxt[e1] = o1;
        if (a2) nxt[e2] = o2;
        if (a3) nxt[e3] = o3;
    } else {
        int idx = (blockIdx.x - binBlocks) * blockDim.x + threadIdx.x;
        if (idx >= total4) return;
        float4 xv = ((const float4*)x)[idx];
        float4 wv = ((const float4*)w)[idx & (DFEAT / 4 - 1)];
        float a, r0, r1, r2, r3;
        a = xv.x * wv.x; r0 = 2.0f * (a > 0.0f ? a : (__expf(a) - 1.0f));
        a = xv.y * wv.y; r1 = 2.0f * (a > 0.0f ? a : (__expf(a) - 1.0f));
        a = xv.z * wv.z; r2 = 2.0f * (a > 0.0f ? a : (__expf(a) - 1.0f));
        a = xv.w * wv.w; r3 = 2.0f * (a > 0.0f ? a : (__expf(a) - 1.0f));
        __half2 h01 = __floats2half2_rn(r0, r1);
        __half2 h23 = __floats2half2_rn(r2, r3);
        uint2 pk;
        pk.x = *(u32*)&h01;
        pk.y = *(u32*)&h23;
        ((uint2*)emb2)[idx] = pk;
    }
}

// Convert linked lists -> fixed-stride slot arrays. One lane per node: 64
// independent pointer chases per wave (vs 2 in the old fused gather), and the
// chase carries only 8B next-pointers, no 256B row loads on the chain.
// Leftover edges beyond CAP (statistically nonexistent at Poisson(16)) stay on
// the list: head[n] is rewritten to the remaining-list position for the gather
// kernel's correctness tail.
__global__ void convert_kernel(const u64* __restrict__ nxt,
                               u64* __restrict__ head,
                               u16* __restrict__ slots,
                               int* __restrict__ cnt, int N) {
    int n = blockIdx.x * blockDim.x + threadIdx.x;
    if (n >= N) return;
    u64 cur = head[n];
    int i = 0;
    while (cur != ENDK && i < CAP) {
        slots[(size_t)n * CAP + i] = (u16)(cur >> 32);
        ++i;
        cur = nxt[(u32)cur];
    }
    cnt[n] = i;
    head[n] = cur;   // ENDK unless degree > CAP
}

// One wave per node; lane holds 2 columns (half2 -> f32 acc). All row loads are
// independent (slot ids known up front): 4 x 256B loads in flight per wave.
__global__ void gather_slot_kernel(const __half* __restrict__ emb2,
                                   const u16* __restrict__ slots,
                                   const int* __restrict__ cnt,
                                   const u64* __restrict__ head,
                                   const u64* __restrict__ nxt,
                                   float* __restrict__ out, int N) {
    int wid = (blockIdx.x * blockDim.x + threadIdx.x) >> 6;
    int lane = threadIdx.x & 63;
    if (wid >= N) return;
    int n = wid;
    int k = cnt[n];
    u32 sid = 0;
    if (lane < k) sid = slots[(size_t)n * CAP + lane];
    float2 acc = make_float2(0.0f, 0.0f);
    int j = 0;
    for (; j + 4 <= k; j += 4) {
        int i0 = __shfl((int)sid, j);
        int i1 = __shfl((int)sid, j + 1);
        int i2 = __shfl((int)sid, j + 2);
        int i3 = __shfl((int)sid, j + 3);
        u32 u0 = ((const u32*)(emb2 + (size_t)i0 * DFEAT))[lane];
        u32 u1 = ((const u32*)(emb2 + (size_t)i1 * DFEAT))[lane];
        u32 u2 = ((const u32*)(emb2 + (size_t)i2 * DFEAT))[lane];
        u32 u3 = ((const u32*)(emb2 + (size_t)i3 * DFEAT))[lane];
        float2 f0 = __half22float2(*(__half2*)&u0);
        float2 f1 = __half22float2(*(__half2*)&u1);
        float2 f2 = __half22float2(*(__half2*)&u2);
        float2 f3 = __half22float2(*(__half2*)&u3);
        acc.x += f0.x + f1.x + f2.x + f3.x;
        acc.y += f0.y + f1.y + f2.y + f3.y;
    }
    for (; j < k; ++j) {
        int i0 = __shfl((int)sid, j);
        u32 u0 = ((const u32*)(emb2 + (size_t)i0 * DFEAT))[lane];
        float2 f0 = __half22float2(*(__half2*)&u0);
        acc.x += f0.x;
        acc.y += f0.y;
    }
    // correctness tail: leftover list for degree > CAP (normally empty)
    u64 cur = head[n];
    while (cur != ENDK) {
        u32 u0 = ((const u32*)(emb2 + (size_t)(cur >> 32) * DFEAT))[lane];
        cur = nxt[(u32)cur];
        float2 f0 = __half22float2(*(__half2*)&u0);
        acc.x += f0.x;
        acc.y += f0.y;
    }
    ((float2*)(out + (size_t)n * DFEAT))[lane] = acc;
}

// Mid path (ws fits lists but not slots): old wave-per-2-nodes list gather.
__global__ void gather_ll_kernel(const __half* __restrict__ emb2,
                                 const u64* __restrict__ head,
                                 const u64* __restrict__ nxt,
                                 float* __restrict__ out, int N) {
    int wid = (blockIdx.x * blockDim.x + threadIdx.x) >> 6;
    int lane = threadIdx.x & 63;
    int nA = wid * 2;
    int nB = nA + 1;
    if (nA >= N) return;
    bool hasB = (nB < N);
    u64 curA = head[nA];
    u64 curB = hasB ? head[nB] : ENDK;
    float2 accA = make_float2(0.0f, 0.0f);
    float2 accB = make_float2(0.0f, 0.0f);
    while (curA != ENDK || curB != ENDK) {
        bool aA = (curA != ENDK);
        bool aB = (curB != ENDK);
        u64 cA = curA, cB = curB;
        u32 uA = 0, uB = 0;
        if (aA) uA = ((const u32*)(emb2 + ((size_t)(cA >> 32)) * DFEAT))[lane];
        if (aB) uB = ((const u32*)(emb2 + ((size_t)(cB >> 32)) * DFEAT))[lane];
        if (aA) curA = nxt[(u32)cA];
        if (aB) curB = nxt[(u32)cB];
        if (aA) {
            float2 f = __half22float2(*(__half2*)&uA);
            accA.x += f.x; accA.y += f.y;
        }
        if (aB) {
            float2 f = __half22float2(*(__half2*)&uB);
            accB.x += f.x; accB.y += f.y;
        }
    }
    ((float2*)(out + (size_t)nA * DFEAT))[lane] = accA;
    if (hasB) ((float2*)(out + (size_t)nB * DFEAT))[lane] = accB;
}

// Fallback if ws too small: fuse elu into gather, fp32 atomic scatter.
__global__ void scatter_fused_kernel(const float* __restrict__ x,
                                     const float* __restrict__ w,
                                     const int* __restrict__ src,
                                     const int* __restrict__ dst,
                                     float* __restrict__ out, int E) {
    int t = blockIdx.x * blockDim.x + threadIdx.x;
    int edge = t >> 5;
    int lane = t & 31;
    if (edge >= E) return;
    int s = src[edge];
    int d = dst[edge];
    float4 xv = ((const float4*)(x + (size_t)s * DFEAT))[lane];
    float4 wv = ((const float4*)w)[lane];
    float4 v;
    float a;
    a = xv.x * wv.x; v.x = 2.0f * (a > 0.0f ? a : (__expf(a) - 1.0f));
    a = xv.y * wv.y; v.y = 2.0f * (a > 0.0f ? a : (__expf(a) - 1.0f));
    a = xv.z * wv.z; v.z = 2.0f * (a > 0.0f ? a : (__expf(a) - 1.0f));
    a = xv.w * wv.w; v.w = 2.0f * (a > 0.0f ? a : (__expf(a) - 1.0f));
    float* op = out + (size_t)d * DFEAT + lane * 4;
    unsafeAtomicAdd(op + 0, v.x);
    unsafeAtomicAdd(op + 1, v.y);
    unsafeAtomicAdd(op + 2, v.z);
    unsafeAtomicAdd(op + 3, v.w);
}

extern "C" void kernel_launch(void* const* d_in, const int* in_sizes, int n_in,
                              void* d_out, int out_size, void* d_ws, size_t ws_size,
                              hipStream_t stream) {
    const float* x   = (const float*)d_in[0];   // graph_embedding [N, 128]
    const float* w   = (const float*)d_in[1];   // weight [1, 128]
    const int*   src = (const int*)d_in[3];     // src [E]
    const int*   dst = (const int*)d_in[4];     // dst [E]
    float* out = (float*)d_out;

    const int ND = in_sizes[0];          // N * 128
    const int N  = ND / DFEAT;           // 50000
    const int E  = in_sizes[2];          // 800000

    size_t emb_bytes   = ((size_t)ND * sizeof(__half) + 15) & ~(size_t)15;  // 12.8 MB
    size_t head_bytes  = ((size_t)N * sizeof(u64) + 15) & ~(size_t)15;      // 400 KB
    size_t nxt_bytes   = ((size_t)E * sizeof(u64) + 15) & ~(size_t)15;      // 6.4 MB
    size_t slot_bytes  = ((size_t)N * CAP * sizeof(u16) + 15) & ~(size_t)15; // 6.4 MB
    size_t cnt_bytes   = ((size_t)N * sizeof(int) + 15) & ~(size_t)15;      // 200 KB
    size_t total_old = emb_bytes + head_bytes + nxt_bytes;
    size_t total_new = total_old + slot_bytes + cnt_bytes;

    int total4 = ND / 4;
    int eluBlocks = (total4 + 255) / 256;
    int binBlocks = (E + 1023) / 1024;   // 4 edges per thread

    if (ws_size >= total_new && N <= 65535) {
        char* p = (char*)d_ws;
        __half* emb2 = (__half*)p;  p += emb_bytes;
        u64*    head = (u64*)p;     p += head_bytes;
        u64*    nxt  = (u64*)p;     p += nxt_bytes;
        u16*    slots = (u16*)p;    p += slot_bytes;
        int*    cnt  = (int*)p;

        hipMemsetAsync(head, 0xFF, (size_t)N * sizeof(u64), stream);

        fused_bin_elu_kernel<<<binBlocks + eluBlocks, 256, 0, stream>>>(
            x, w, emb2, total4, src, dst, E, head, nxt, binBlocks);

        convert_kernel<<<(N + 255) / 256, 256, 0, stream>>>(nxt, head, slots, cnt, N);

        long long thr = (long long)N * 64;
        gather_slot_kernel<<<(int)((thr + 255) / 256), 256, 0, stream>>>(
            emb2, slots, cnt, head, nxt, out, N);
    } else if (ws_size >= total_old) {
        char* p = (char*)d_ws;
        __half* emb2 = (__half*)p;  p += emb_bytes;
        u64*    head = (u64*)p;     p += head_bytes;
        u64*    nxt  = (u64*)p;

        hipMemsetAsync(head, 0xFF, (size_t)N * sizeof(u64), stream);

        fused_bin_elu_kernel<<<binBlocks + eluBlocks, 256, 0, stream>>>(
            x, w, emb2, total4, src, dst, E, head, nxt, binBlocks);

        long long waves = (N + 1) / 2;
        long long thr = waves * 64;
        gather_ll_kernel<<<(int)((thr + 255) / 256), 256, 0, stream>>>(
            emb2, head, nxt, out, N);
    } else {
        hipMemsetAsync(d_out, 0, (size_t)out_size * sizeof(float), stream);
        long long threads = (long long)E * 32;
        scatter_fused_kernel<<<(int)((threads + 255) / 256), 256, 0, stream>>>(x, w, src, dst, out, E);
    }
}

// Round 2
// 161.036 us; speedup vs baseline: 1.1153x; 1.0558x over previous
//
#include <hip/hip_runtime.h>
#include <hip/hip_fp16.h>
#include <math.h>

#define DFEAT 128
#define CAP 64
#define CSTR 8   // cnt stride in u32: one node per 32B sector (anti-serialization pad)
typedef unsigned long long u64;
typedef unsigned int u32;
typedef unsigned short u16;
#define ENDK 0xFFFFFFFFFFFFFFFFULL

// K1, split by block range. Bin blocks FIRST (latency/atomic-bound phase fills
// CUs immediately; BW-bound ELU streams behind it).
//  - blocks [0, binBlocks): slot binning, 4 strided edges per thread:
//      idx = atomicAdd(&cnt[d*CSTR], 1); slots[d*CAP+idx] = src
//      overflow (idx >= CAP): u32 linked list, 0-sentinel (memset(0) inits all)
//  - blocks [binBlocks, ..): emb2[i] = fp16( 2 * elu(x[i] * w[i % D]) )
__global__ void fused_bin_elu_kernel(const float* __restrict__ x,
                                     const float* __restrict__ w,
                                     __half* __restrict__ emb2, int total4,
                                     const int* __restrict__ src,
                                     const int* __restrict__ dst, int E,
                                     u32* __restrict__ cnt,
                                     u32* __restrict__ head,
                                     u32* __restrict__ nxt,
                                     u16* __restrict__ slots,
                                     int binBlocks) {
    if ((int)blockIdx.x < binBlocks) {
        int base = blockIdx.x * 1024 + threadIdx.x;   // 4 edges, stride 256
        int e0 = base, e1 = base + 256, e2 = base + 512, e3 = base + 768;
        bool a0 = e0 < E, a1 = e1 < E, a2 = e2 < E, a3 = e3 < E;
        int s0 = 0, s1 = 0, s2 = 0, s3 = 0, d0 = 0, d1 = 0, d2 = 0, d3 = 0;
        if (a0) { s0 = src[e0]; d0 = dst[e0]; }
        if (a1) { s1 = src[e1]; d1 = dst[e1]; }
        if (a2) { s2 = src[e2]; d2 = dst[e2]; }
        if (a3) { s3 = src[e3]; d3 = dst[e3]; }
        u32 i0 = 0, i1 = 0, i2 = 0, i3 = 0;
        if (a0) i0 = atomicAdd(&cnt[(size_t)d0 * CSTR], 1u);
        if (a1) i1 = atomicAdd(&cnt[(size_t)d1 * CSTR], 1u);
        if (a2) i2 = atomicAdd(&cnt[(size_t)d2 * CSTR], 1u);
        if (a3) i3 = atomicAdd(&cnt[(size_t)d3 * CSTR], 1u);
        if (a0) {
            if (i0 < CAP) slots[(size_t)d0 * CAP + i0] = (u16)s0;
            else { u32 o = atomicExch(&head[d0], (u32)(e0 + 1)); nxt[e0] = o; }
        }
        if (a1) {
            if (i1 < CAP) slots[(size_t)d1 * CAP + i1] = (u16)s1;
            else { u32 o = atomicExch(&head[d1], (u32)(e1 + 1)); nxt[e1] = o; }
        }
        if (a2) {
            if (i2 < CAP) slots[(size_t)d2 * CAP + i2] = (u16)s2;
            else { u32 o = atomicExch(&head[d2], (u32)(e2 + 1)); nxt[e2] = o; }
        }
        if (a3) {
            if (i3 < CAP) slots[(size_t)d3 * CAP + i3] = (u16)s3;
            else { u32 o = atomicExch(&head[d3], (u32)(e3 + 1)); nxt[e3] = o; }
        }
    } else {
        int idx = (blockIdx.x - binBlocks) * blockDim.x + threadIdx.x;
        if (idx >= total4) return;
        float4 xv = ((const float4*)x)[idx];
        float4 wv = ((const float4*)w)[idx & (DFEAT / 4 - 1)];
        float a, r0, r1, r2, r3;
        a = xv.x * wv.x; r0 = 2.0f * (a > 0.0f ? a : (__expf(a) - 1.0f));
        a = xv.y * wv.y; r1 = 2.0f * (a > 0.0f ? a : (__expf(a) - 1.0f));
        a = xv.z * wv.z; r2 = 2.0f * (a > 0.0f ? a : (__expf(a) - 1.0f));
        a = xv.w * wv.w; r3 = 2.0f * (a > 0.0f ? a : (__expf(a) - 1.0f));
        __half2 h01 = __floats2half2_rn(r0, r1);
        __half2 h23 = __floats2half2_rn(r2, r3);
        uint2 pk;
        pk.x = *(u32*)&h01;
        pk.y = *(u32*)&h23;
        ((uint2*)emb2)[idx] = pk;
    }
}

// One wave per node; lane holds 2 columns (half2 -> f32 acc). Slot ids are
// known up front -> 8 independent 256B row loads in flight per wave.
__global__ void gather_slot_kernel(const __half* __restrict__ emb2,
                                   const u16* __restrict__ slots,
                                   const u32* __restrict__ cnt,
                                   const u32* __restrict__ head,
                                   const u32* __restrict__ nxt,
                                   const int* __restrict__ src,
                                   float* __restrict__ out, int N) {
    int wid = (blockIdx.x * blockDim.x + threadIdx.x) >> 6;
    int lane = threadIdx.x & 63;
    if (wid >= N) return;
    int n = wid;
    u32 kc = cnt[(size_t)n * CSTR];
    int k = kc < CAP ? (int)kc : CAP;
    u32 sid = 0;
    if (lane < k) sid = slots[(size_t)n * CAP + lane];
    float2 acc = make_float2(0.0f, 0.0f);
    int j = 0;
    for (; j + 8 <= k; j += 8) {
        int i0 = __shfl((int)sid, j);
        int i1 = __shfl((int)sid, j + 1);
        int i2 = __shfl((int)sid, j + 2);
        int i3 = __shfl((int)sid, j + 3);
        int i4 = __shfl((int)sid, j + 4);
        int i5 = __shfl((int)sid, j + 5);
        int i6 = __shfl((int)sid, j + 6);
        int i7 = __shfl((int)sid, j + 7);
        u32 u0 = ((const u32*)(emb2 + (size_t)i0 * DFEAT))[lane];
        u32 u1 = ((const u32*)(emb2 + (size_t)i1 * DFEAT))[lane];
        u32 u2 = ((const u32*)(emb2 + (size_t)i2 * DFEAT))[lane];
        u32 u3 = ((const u32*)(emb2 + (size_t)i3 * DFEAT))[lane];
        u32 u4 = ((const u32*)(emb2 + (size_t)i4 * DFEAT))[lane];
        u32 u5 = ((const u32*)(emb2 + (size_t)i5 * DFEAT))[lane];
        u32 u6 = ((const u32*)(emb2 + (size_t)i6 * DFEAT))[lane];
        u32 u7 = ((const u32*)(emb2 + (size_t)i7 * DFEAT))[lane];
        float2 f0 = __half22float2(*(__half2*)&u0);
        float2 f1 = __half22float2(*(__half2*)&u1);
        float2 f2 = __half22float2(*(__half2*)&u2);
        float2 f3 = __half22float2(*(__half2*)&u3);
        float2 f4 = __half22float2(*(__half2*)&u4);
        float2 f5 = __half22float2(*(__half2*)&u5);
        float2 f6 = __half22float2(*(__half2*)&u6);
        float2 f7 = __half22float2(*(__half2*)&u7);
        acc.x += (f0.x + f1.x) + (f2.x + f3.x) + (f4.x + f5.x) + (f6.x + f7.x);
        acc.y += (f0.y + f1.y) + (f2.y + f3.y) + (f4.y + f5.y) + (f6.y + f7.y);
    }
    for (; j < k; ++j) {
        int i0 = __shfl((int)sid, j);
        u32 u0 = ((const u32*)(emb2 + (size_t)i0 * DFEAT))[lane];
        float2 f0 = __half22float2(*(__half2*)&u0);
        acc.x += f0.x;
        acc.y += f0.y;
    }
    // correctness tail: overflow list for degree > CAP (normally empty)
    if (kc > CAP) {
        u32 cur = head[n];
        while (cur != 0) {
            u32 e = cur - 1;
            int s = src[e];
            u32 u0 = ((const u32*)(emb2 + (size_t)s * DFEAT))[lane];
            cur = nxt[e];
            float2 f0 = __half22float2(*(__half2*)&u0);
            acc.x += f0.x;
            acc.y += f0.y;
        }
    }
    ((float2*)(out + (size_t)n * DFEAT))[lane] = acc;
}

// ---------- mid fallback path (ws fits u64 lists but not slots) ----------
__global__ void bin_elu_ll_kernel(const float* __restrict__ x,
                                  const float* __restrict__ w,
                                  __half* __restrict__ emb2, int total4,
                                  const int* __restrict__ src,
                                  const int* __restrict__ dst, int E,
                                  u64* __restrict__ head,
                                  u64* __restrict__ nxt,
                                  int binBlocks) {
    if ((int)blockIdx.x < binBlocks) {
        int base = blockIdx.x * 1024 + threadIdx.x;
        for (int q = 0; q < 4; ++q) {
            int e = base + q * 256;
            if (e < E) {
                int s = src[e];
                int d = dst[e];
                u64 old = atomicExch(&head[d], ((u64)(u32)s << 32) | (u32)e);
                nxt[e] = old;
            }
        }
    } else {
        int idx = (blockIdx.x - binBlocks) * blockDim.x + threadIdx.x;
        if (idx >= total4) return;
        float4 xv = ((const float4*)x)[idx];
        float4 wv = ((const float4*)w)[idx & (DFEAT / 4 - 1)];
        float a, r0, r1, r2, r3;
        a = xv.x * wv.x; r0 = 2.0f * (a > 0.0f ? a : (__expf(a) - 1.0f));
        a = xv.y * wv.y; r1 = 2.0f * (a > 0.0f ? a : (__expf(a) - 1.0f));
        a = xv.z * wv.z; r2 = 2.0f * (a > 0.0f ? a : (__expf(a) - 1.0f));
        a = xv.w * wv.w; r3 = 2.0f * (a > 0.0f ? a : (__expf(a) - 1.0f));
        __half2 h01 = __floats2half2_rn(r0, r1);
        __half2 h23 = __floats2half2_rn(r2, r3);
        uint2 pk;
        pk.x = *(u32*)&h01;
        pk.y = *(u32*)&h23;
        ((uint2*)emb2)[idx] = pk;
    }
}

__global__ void gather_ll_kernel(const __half* __restrict__ emb2,
                                 const u64* __restrict__ head,
                                 const u64* __restrict__ nxt,
                                 float* __restrict__ out, int N) {
    int wid = (blockIdx.x * blockDim.x + threadIdx.x) >> 6;
    int lane = threadIdx.x & 63;
    int nA = wid * 2;
    int nB = nA + 1;
    if (nA >= N) return;
    bool hasB = (nB < N);
    u64 curA = head[nA];
    u64 curB = hasB ? head[nB] : ENDK;
    float2 accA = make_float2(0.0f, 0.0f);
    float2 accB = make_float2(0.0f, 0.0f);
    while (curA != ENDK || curB != ENDK) {
        bool aA = (curA != ENDK);
        bool aB = (curB != ENDK);
        u64 cA = curA, cB = curB;
        u32 uA = 0, uB = 0;
        if (aA) uA = ((const u32*)(emb2 + ((size_t)(cA >> 32)) * DFEAT))[lane];
        if (aB) uB = ((const u32*)(emb2 + ((size_t)(cB >> 32)) * DFEAT))[lane];
        if (aA) curA = nxt[(u32)cA];
        if (aB) curB = nxt[(u32)cB];
        if (aA) {
            float2 f = __half22float2(*(__half2*)&uA);
            accA.x += f.x; accA.y += f.y;
        }
        if (aB) {
            float2 f = __half22float2(*(__half2*)&uB);
            accB.x += f.x; accB.y += f.y;
        }
    }
    ((float2*)(out + (size_t)nA * DFEAT))[lane] = accA;
    if (hasB) ((float2*)(out + (size_t)nB * DFEAT))[lane] = accB;
}

// Fallback if ws too small: fuse elu into gather, fp32 atomic scatter.
__global__ void scatter_fused_kernel(const float* __restrict__ x,
                                     const float* __restrict__ w,
                                     const int* __restrict__ src,
                                     const int* __restrict__ dst,
                                     float* __restrict__ out, int E) {
    int t = blockIdx.x * blockDim.x + threadIdx.x;
    int edge = t >> 5;
    int lane = t & 31;
    if (edge >= E) return;
    int s = src[edge];
    int d = dst[edge];
    float4 xv = ((const float4*)(x + (size_t)s * DFEAT))[lane];
    float4 wv = ((const float4*)w)[lane];
    float4 v;
    float a;
    a = xv.x * wv.x; v.x = 2.0f * (a > 0.0f ? a : (__expf(a) - 1.0f));
    a = xv.y * wv.y; v.y = 2.0f * (a > 0.0f ? a : (__expf(a) - 1.0f));
    a = xv.z * wv.z; v.z = 2.0f * (a > 0.0f ? a : (__expf(a) - 1.0f));
    a = xv.w * wv.w; v.w = 2.0f * (a > 0.0f ? a : (__expf(a) - 1.0f));
    float* op = out + (size_t)d * DFEAT + lane * 4;
    unsafeAtomicAdd(op + 0, v.x);
    unsafeAtomicAdd(op + 1, v.y);
    unsafeAtomicAdd(op + 2, v.z);
    unsafeAtomicAdd(op + 3, v.w);
}

extern "C" void kernel_launch(void* const* d_in, const int* in_sizes, int n_in,
                              void* d_out, int out_size, void* d_ws, size_t ws_size,
                              hipStream_t stream) {
    const float* x   = (const float*)d_in[0];   // graph_embedding [N, 128]
    const float* w   = (const float*)d_in[1];   // weight [1, 128]
    const int*   src = (const int*)d_in[3];     // src [E]
    const int*   dst = (const int*)d_in[4];     // dst [E]
    float* out = (float*)d_out;

    const int ND = in_sizes[0];          // N * 128
    const int N  = ND / DFEAT;           // 50000
    const int E  = in_sizes[2];          // 800000

    size_t emb_bytes   = ((size_t)ND * sizeof(__half) + 15) & ~(size_t)15;        // 12.8 MB
    size_t cnt_bytes   = ((size_t)N * CSTR * sizeof(u32) + 15) & ~(size_t)15;     // 1.6 MB
    size_t head_bytes  = ((size_t)N * sizeof(u32) + 15) & ~(size_t)15;            // 200 KB
    size_t nxt_bytes   = ((size_t)E * sizeof(u32) + 15) & ~(size_t)15;            // 3.2 MB
    size_t slot_bytes  = ((size_t)N * CAP * sizeof(u16) + 15) & ~(size_t)15;      // 6.4 MB
    size_t total_new = emb_bytes + cnt_bytes + head_bytes + nxt_bytes + slot_bytes; // 24.2 MB

    size_t head64_bytes = ((size_t)N * sizeof(u64) + 15) & ~(size_t)15;
    size_t nxt64_bytes  = ((size_t)E * sizeof(u64) + 15) & ~(size_t)15;
    size_t total_old = emb_bytes + head64_bytes + nxt64_bytes;                    // 19.6 MB

    int total4 = ND / 4;
    int eluBlocks = (total4 + 255) / 256;
    int binBlocks = (E + 1023) / 1024;   // 4 edges per thread

    if (ws_size >= total_new && N <= 65536) {   // u16 slots hold src in [0, N)
        char* p = (char*)d_ws;
        __half* emb2 = (__half*)p;  p += emb_bytes;
        u32*    cnt  = (u32*)p;     p += cnt_bytes;
        u32*    head = (u32*)p;     p += head_bytes;
        u32*    nxt  = (u32*)p;     p += nxt_bytes;
        u16*    slots = (u16*)p;

        // one memset covers cnt (0 counts) AND head (0 = empty-list sentinel)
        hipMemsetAsync(cnt, 0, cnt_bytes + head_bytes, stream);

        fused_bin_elu_kernel<<<binBlocks + eluBlocks, 256, 0, stream>>>(
            x, w, emb2, total4, src, dst, E, cnt, head, nxt, slots, binBlocks);

        long long thr = (long long)N * 64;
        gather_slot_kernel<<<(int)((thr + 255) / 256), 256, 0, stream>>>(
            emb2, slots, cnt, head, nxt, src, out, N);
    } else if (ws_size >= total_old) {
        char* p = (char*)d_ws;
        __half* emb2 = (__half*)p;  p += emb_bytes;
        u64*    head = (u64*)p;     p += head64_bytes;
        u64*    nxt  = (u64*)p;

        hipMemsetAsync(head, 0xFF, (size_t)N * sizeof(u64), stream);

        bin_elu_ll_kernel<<<binBlocks + eluBlocks, 256, 0, stream>>>(
            x, w, emb2, total4, src, dst, E, head, nxt, binBlocks);

        long long waves = (N + 1) / 2;
        long long thr = waves * 64;
        gather_ll_kernel<<<(int)((thr + 255) / 256), 256, 0, stream>>>(
            emb2, head, nxt, out, N);
    } else {
        hipMemsetAsync(d_out, 0, (size_t)out_size * sizeof(float), stream);
        long long threads = (long long)E * 32;
        scatter_fused_kernel<<<(int)((threads + 255) / 256), 256, 0, stream>>>(x, w, src, dst, out, E);
    }
}